// Round 7
// baseline (358.423 us; speedup 1.0000x reference)
//
#include <hip/hip_runtime.h>

#define N_    16
#define DIN   24
#define DOUT  26
#define CIN   64
#define COUT  128
#define NGRP  8
#define EPS   1e-5f

// ws layout (bytes):
//   [0, 1024)       : float stats[N_][NGRP][2] (sum, sumsq) -- zeroed each launch
//   [1280, 443648)  : fp16 Kf[27][4][4][64][8]  (32x32 MFMA B-fragment order)
#define STATS_OFF 0
#define KF_OFF    1280

typedef _Float16 half8_t  __attribute__((ext_vector_type(8)));
typedef float    f32x16_t __attribute__((ext_vector_type(16)));
typedef float    f32x4_t  __attribute__((ext_vector_type(4)));   // native vec for
                                                                 // nontemporal builtins
// ---- build Kf in 32x32x16 B-fragment order + zero stats ----
// frag (tap, ckg, nf): element j of lane: k(ci) = ckg*16 + (lane>>5)*8 + j,
// n(co) = nf*32 + (lane&31).   t = ((tap*4 + ckg)*4 + nf)*64 + lane.
__global__ __launch_bounds__(256) void convert_k_kernel(
    const float* __restrict__ K, _Float16* __restrict__ Kf, float* __restrict__ stats)
{
    int t = blockIdx.x * 256 + threadIdx.x;
    if (blockIdx.x == 0 && threadIdx.x < N_ * NGRP * 2) stats[threadIdx.x] = 0.0f;
    if (t >= 27 * 4 * 4 * 64) return;
    const int lane = t & 63;
    const int nf   = (t >> 6) & 3;
    const int ckg  = (t >> 8) & 3;
    const int tap  = t >> 10;                        // 0..26 = ad*9+ah*3+aw
    const int ci0  = ckg * 16 + (lane >> 5) * 8;
    const int co   = nf * 32 + (lane & 31);
    half8_t h;
    #pragma unroll
    for (int j = 0; j < 8; ++j)
        h[j] = (_Float16)K[(size_t)(tap * CIN + ci0 + j) * COUT + co];
    *(half8_t*)(Kf + (size_t)t * 8) = h;
}

// ==== conv + ReLU + group sums. Wave = one cout-frag (nf=wv), M = 4 h-rows ====
// Block (n, d, h-quad), NATURAL block order. Each B-fragment (1 global 16B
// load/lane) feeds 4 MFMAs (one per h-row) -> Kf L2 request volume per block
// = 432 KB = one copy of Kf.
// REGISTER BUDGET (round-3/4 lesson): gfx950 VGPR/AGPR file is unified;
// acc[4] = 64 AGPRs. (256,4) capped total at 128 -> spill (FETCH 495 MB,
// WRITE 927 MB, 2x slowdown). (256,3) -> VGPR 84, no spill, 179 us.
// Epilogue y stores are NONTEMPORAL: y is 144 MB write-once (next touched a
// full kernel later) -- keep it from evicting x halo lines out of L2
// (FETCH 100 MB vs ~58 MB ideal is the symptom).
// Phase ph in {0,1}: stage ci ph*32..+31 for all 18 (ad,hh) rows (fp32 src,
// cvt in-register), barrier, run all 27 taps x 2 k16-steps; acc persists.
// LDS row: 28 w-slots; slot stride 40 half (32 ci data + 8 pad; 80 B keeps
// b128 16-B aligned). 40,320 B LDS.
__global__ __launch_bounds__(256, 3) void conv_mfma_kernel(
    const float* __restrict__ x, const _Float16* __restrict__ Kf,
    float* __restrict__ y, float* __restrict__ stats)
{
    __shared__ __align__(16) _Float16 xs[18 * 28 * 40];   // 40,320 B
    __shared__ float gsum[NGRP], gsq[NGRP];

    const int bid = blockIdx.x;
    const int n   = bid / (DOUT * 7);
    const int rem = bid % (DOUT * 7);
    const int d   = rem / 7;
    const int hb  = (rem % 7) * 4;
    const int tid = threadIdx.x;

    if (tid < NGRP) { gsum[tid] = 0.0f; gsq[tid] = 0.0f; }

    const int lane = tid & 63;
    const int wv   = tid >> 6;          // nf: couts wv*32 .. wv*32+31
    const int col  = lane & 31;         // A: m(=w) ; B/C/D: n(cout in frag)
    const int hi   = lane >> 5;         // k-half selector

    int aofs[3];
    #pragma unroll
    for (int aw = 0; aw < 3; ++aw) {
        int sl = col - aw + 2; if (sl > 27) sl = 27;   // slot 27 always zero-staged
        aofs[aw] = sl * 40 + hi * 8;
    }

    f32x16_t acc[4];
    #pragma unroll
    for (int q = 0; q < 4; ++q) acc[q] = (f32x16_t)(0.0f);

    const _Float16* Kfl = Kf + (size_t)lane * 8 + (size_t)wv * 512;

    for (int ph = 0; ph < 2; ++ph) {
        // ---- stage this phase's 32 ci: 18*28*4 = 2016 16-B chunks ----
        for (int c = tid; c < 2016; c += 256) {
            const int s    = c / 112;        // s = ad*6 + hs
            const int rr   = c % 112;
            const int slot = rr >> 2;        // source w = slot - 2
            const int ch   = rr & 3;
            const int dd = d - s / 6;
            const int hh = hb + (s % 6) - 2;
            const int w  = slot - 2;
            half8_t v = {};
            if (dd >= 0 && dd < DIN && hh >= 0 && hh < DIN && w >= 0 && w < DIN) {
                const float* src = x + ((size_t)(((n * DIN + dd) * DIN + hh) * DIN + w)) * CIN
                                     + ph * 32 + ch * 8;
                const float4 a = *(const float4*)(src);
                const float4 b = *(const float4*)(src + 4);
                v[0] = (_Float16)a.x; v[1] = (_Float16)a.y; v[2] = (_Float16)a.z; v[3] = (_Float16)a.w;
                v[4] = (_Float16)b.x; v[5] = (_Float16)b.y; v[6] = (_Float16)b.z; v[7] = (_Float16)b.w;
            }
            *(half8_t*)(xs + s * 1120 + slot * 40 + ch * 8) = v;
        }
        __syncthreads();

        // ---- all 27 taps, 2 k16-steps within this ci-half ----
        // B layout offset: (((tap)*4 + ckg)*4 + nf)*512 + lane*8, ckg = ph*2+ck.
        for (int ad = 0; ad < 3; ++ad) {
            #pragma unroll
            for (int ah = 0; ah < 3; ++ah) {
                const int sb  = (ad * 6 - ah + 2) * 1120;   // + q*1120 per h-row
                const int tap = (ad * 3 + ah) * 3;
                #pragma unroll
                for (int aw = 0; aw < 3; ++aw) {
                    #pragma unroll
                    for (int ck = 0; ck < 2; ++ck) {
                        half8_t b = *(const half8_t*)(
                            Kfl + (size_t)(((tap + aw) * 4 + ph * 2 + ck) * 4) * 512);
                        #pragma unroll
                        for (int q = 0; q < 4; ++q) {
                            half8_t a = *(const half8_t*)(xs + sb + q * 1120 + aofs[aw] + ck * 16);
                            acc[q] = __builtin_amdgcn_mfma_f32_32x32x16_f16(a, b, acc[q], 0, 0, 0);
                        }
                    }
                }
            }
        }
        if (ph == 0) __syncthreads();   // protect LDS before re-staging
    }

    // epilogue. C/D (HW-verified): col(cout)=lane&31, row(w)=(reg&3)+8*(reg>>2)+4*hi
    #pragma unroll
    for (int q = 0; q < 4; ++q) {
        const int hrow = hb + q;
        if (hrow >= DOUT) continue;
        const size_t rowbase = (((size_t)(n * DOUT + d)) * DOUT + hrow) * (DOUT * COUT);
        const int cout = wv * 32 + col;
        float ls = 0.f, lsq = 0.f;
        #pragma unroll
        for (int reg = 0; reg < 16; ++reg) {
            const int wout = (reg & 3) + 8 * (reg >> 2) + 4 * hi;
            float v = fmaxf(acc[q][reg], 0.0f);
            if (wout < DOUT) {
                __builtin_nontemporal_store(v, &y[rowbase + (size_t)wout * COUT + cout]);
                ls += v; lsq += v * v;
            }
        }
        // cohort sharing one GN group: same (col>>4) -> xor {1,2,4,8,32}
        #pragma unroll
        for (int off = 1; off < 16; off <<= 1) {
            ls  += __shfl_xor(ls, off);
            lsq += __shfl_xor(lsq, off);
        }
        ls  += __shfl_xor(ls, 32);
        lsq += __shfl_xor(lsq, 32);
        if (lane == 0 || lane == 16) {
            const int g = wv * 2 + (col >> 4);   // 8 groups of 16 couts
            atomicAdd(&gsum[g], ls);
            atomicAdd(&gsq[g], lsq);
        }
    }
    __syncthreads();
    if (tid < NGRP) {
        atomicAdd(&stats[(n * NGRP + tid) * 2 + 0], gsum[tid]);
        atomicAdd(&stats[(n * NGRP + tid) * 2 + 1], gsq[tid]);
    }
}

// ---- elementwise normalize: grid-stride, 2048 blocks (8/CU = full occupancy) ----
// Stride 2048*256 = 524,288 is divisible by 32 (= COUT/4 float4-columns), so
// each thread's co/g are LOOP-INVARIANT -> scale/bias hoisted out of the loop.
// y is 288 MB of single-use streaming traffic -> nontemporal load+store keeps
// it out of L2 (native f32x4_t: HIP float4 is a class type the builtin rejects).
// Previous version (35k blocks, 1 float4/thread) ran at ~2 TB/s.
#define GN_GRID 2048
__global__ __launch_bounds__(256) void gn_apply_kernel(
    float* __restrict__ y, const float* __restrict__ stats,
    const float* __restrict__ scale, const float* __restrict__ bias)
{
    const int total4 = N_ * DOUT * DOUT * DOUT * (COUT / 4);   // 8,998,912
    const float invN = 1.0f / (float)(DOUT * DOUT * DOUT * (COUT / NGRP));

    const int t = (blockIdx.x * 256 + threadIdx.x) & 31;       // loop-invariant
    const int g = t >> 2;
    const f32x4_t sc = *(const f32x4_t*)(scale + t * 4);
    const f32x4_t bi = *(const f32x4_t*)(bias + t * 4);

    for (int i = blockIdx.x * 256 + threadIdx.x; i < total4; i += GN_GRID * 256) {
        const int n  = i / (DOUT * DOUT * DOUT * (COUT / 4));
        const float s  = stats[(n * NGRP + g) * 2 + 0];
        const float sq = stats[(n * NGRP + g) * 2 + 1];
        const float mean = s * invN;
        const float rstd = rsqrtf(sq * invN - mean * mean + EPS);

        f32x4_t v = __builtin_nontemporal_load((const f32x4_t*)y + i);
        v = (v - mean) * rstd * sc + bi;
        __builtin_nontemporal_store(v, (f32x4_t*)y + i);
    }
}

extern "C" void kernel_launch(void* const* d_in, const int* in_sizes, int n_in,
                              void* d_out, int out_size, void* d_ws, size_t ws_size,
                              hipStream_t stream) {
    const float* x     = (const float*)d_in[0];
    const float* K     = (const float*)d_in[1];
    const float* scale = (const float*)d_in[2];
    const float* bias  = (const float*)d_in[3];
    float* y = (float*)d_out;

    float*    stats = (float*)((char*)d_ws + STATS_OFF);
    _Float16* Kf    = (_Float16*)((char*)d_ws + KF_OFF);

    convert_k_kernel<<<108, 256, 0, stream>>>(K, Kf, stats);
    conv_mfma_kernel<<<N_ * DOUT * 7, 256, 0, stream>>>(x, Kf, y, stats);
    gn_apply_kernel<<<GN_GRID, 256, 0, stream>>>(y, stats, scale, bias);
}

// Round 8
// 356.502 us; speedup vs baseline: 1.0054x; 1.0054x over previous
//
#include <hip/hip_runtime.h>

#define N_    16
#define DIN   24
#define DOUT  26
#define CIN   64
#define COUT  128
#define NGRP  8
#define EPS   1e-5f

// ws layout (bytes):
//   [0, 1024)       : float stats[N_][NGRP][2] (sum, sumsq) -- zeroed each launch
//   [1280, 443648)  : fp16 Kf[27][4][4][64][8]  (32x32 MFMA B-fragment order)
#define STATS_OFF 0
#define KF_OFF    1280

typedef _Float16 half8_t  __attribute__((ext_vector_type(8)));
typedef float    f32x16_t __attribute__((ext_vector_type(16)));

// ---- build Kf in 32x32x16 B-fragment order + zero stats ----
// frag (tap, ckg, nf): element j of lane: k(ci) = ckg*16 + (lane>>5)*8 + j,
// n(co) = nf*32 + (lane&31).   t = ((tap*4 + ckg)*4 + nf)*64 + lane.
__global__ __launch_bounds__(256) void convert_k_kernel(
    const float* __restrict__ K, _Float16* __restrict__ Kf, float* __restrict__ stats)
{
    int t = blockIdx.x * 256 + threadIdx.x;
    if (blockIdx.x == 0 && threadIdx.x < N_ * NGRP * 2) stats[threadIdx.x] = 0.0f;
    if (t >= 27 * 4 * 4 * 64) return;
    const int lane = t & 63;
    const int nf   = (t >> 6) & 3;
    const int ckg  = (t >> 8) & 3;
    const int tap  = t >> 10;                        // 0..26 = ad*9+ah*3+aw
    const int ci0  = ckg * 16 + (lane >> 5) * 8;
    const int co   = nf * 32 + (lane & 31);
    half8_t h;
    #pragma unroll
    for (int j = 0; j < 8; ++j)
        h[j] = (_Float16)K[(size_t)(tap * CIN + ci0 + j) * COUT + co];
    *(half8_t*)(Kf + (size_t)t * 8) = h;
}

// ==== conv + ReLU + group sums. Wave = one cout-frag (nf=wv), M = 4 h-rows ====
// Block (n, d, h-quad), NATURAL block order (round-3: swizzle destroyed L2
// locality). Each B-fragment feeds 4 MFMAs -> Kf L2 volume = 1 copy/block.
// REGISTER BUDGET (round-3/4 lesson): unified VGPR/AGPR file; acc[4] = 64
// AGPRs; (256,4) cap 128 -> spill catastrophe; (256,3) -> no spill.
// A-ROW REGISTER CACHE (round-8): per ad, the 12 (ah,q) MFMA pairs read only
// 6 distinct LDS rows (row = ad*6 + q-ah+2, q-ah+2 in [0,5]).  Loop order
// ad->aw->ck: load ar[0..5] once (6 ds_read_b128), then 3 ah x 4 q MFMAs index
// ar[q-ah+2] (compile-time const).  LDS reads/phase 216 -> 108; LDS pipe was
// the largest consumer (~47% of cycles: 432 reads x 8 cyc x 4 waves/block).
// +24 VGPR for ar[6] -- watch FETCH/WRITE for spill signature.
// Phase ph in {0,1}: stage ci ph*32..+31 for all 18 (ad,hh) rows (fp32 src,
// cvt in-register), barrier, run all 27 taps x 2 k16-steps; acc persists.
// LDS row: 28 w-slots; slot stride 40 half (32 ci data + 8 pad; 80 B keeps
// b128 16-B aligned). 40,320 B LDS.
__global__ __launch_bounds__(256, 3) void conv_mfma_kernel(
    const float* __restrict__ x, const _Float16* __restrict__ Kf,
    float* __restrict__ y, float* __restrict__ stats)
{
    __shared__ __align__(16) _Float16 xs[18 * 28 * 40];   // 40,320 B
    __shared__ float gsum[NGRP], gsq[NGRP];

    const int bid = blockIdx.x;
    const int n   = bid / (DOUT * 7);
    const int rem = bid % (DOUT * 7);
    const int d   = rem / 7;
    const int hb  = (rem % 7) * 4;
    const int tid = threadIdx.x;

    if (tid < NGRP) { gsum[tid] = 0.0f; gsq[tid] = 0.0f; }

    const int lane = tid & 63;
    const int wv   = tid >> 6;          // nf: couts wv*32 .. wv*32+31
    const int col  = lane & 31;         // A: m(=w) ; B/C/D: n(cout in frag)
    const int hi   = lane >> 5;         // k-half selector

    int aofs[3];
    #pragma unroll
    for (int aw = 0; aw < 3; ++aw) {
        int sl = col - aw + 2; if (sl > 27) sl = 27;   // slot 27 always zero-staged
        aofs[aw] = sl * 40 + hi * 8;
    }

    f32x16_t acc[4];
    #pragma unroll
    for (int q = 0; q < 4; ++q) acc[q] = (f32x16_t)(0.0f);

    const _Float16* Kfl = Kf + (size_t)lane * 8 + (size_t)wv * 512;

    for (int ph = 0; ph < 2; ++ph) {
        // ---- stage this phase's 32 ci: 18*28*4 = 2016 16-B chunks ----
        for (int c = tid; c < 2016; c += 256) {
            const int s    = c / 112;        // s = ad*6 + hs
            const int rr   = c % 112;
            const int slot = rr >> 2;        // source w = slot - 2
            const int ch   = rr & 3;
            const int dd = d - s / 6;
            const int hh = hb + (s % 6) - 2;
            const int w  = slot - 2;
            half8_t v = {};
            if (dd >= 0 && dd < DIN && hh >= 0 && hh < DIN && w >= 0 && w < DIN) {
                const float* src = x + ((size_t)(((n * DIN + dd) * DIN + hh) * DIN + w)) * CIN
                                     + ph * 32 + ch * 8;
                const float4 a = *(const float4*)(src);
                const float4 b = *(const float4*)(src + 4);
                v[0] = (_Float16)a.x; v[1] = (_Float16)a.y; v[2] = (_Float16)a.z; v[3] = (_Float16)a.w;
                v[4] = (_Float16)b.x; v[5] = (_Float16)b.y; v[6] = (_Float16)b.z; v[7] = (_Float16)b.w;
            }
            *(half8_t*)(xs + s * 1120 + slot * 40 + ch * 8) = v;
        }
        __syncthreads();

        // ---- all 27 taps, 2 k16-steps within this ci-half ----
        // B offset: (((ad*3+ah)*3 + aw)*4 + ph*2 + ck)*4*512 (+wv*512 in Kfl).
        for (int ad = 0; ad < 3; ++ad) {
            const int rbase = ad * 6 * 1120;
            #pragma unroll
            for (int aw = 0; aw < 3; ++aw) {
                #pragma unroll
                for (int ck = 0; ck < 2; ++ck) {
                    half8_t ar[6];
                    #pragma unroll
                    for (int v = 0; v < 6; ++v)
                        ar[v] = *(const half8_t*)(xs + rbase + v * 1120 + aofs[aw] + ck * 16);
                    #pragma unroll
                    for (int ah = 0; ah < 3; ++ah) {
                        half8_t b = *(const half8_t*)(
                            Kfl + (size_t)((((ad * 3 + ah) * 3 + aw) * 4 + ph * 2 + ck) * 4) * 512);
                        #pragma unroll
                        for (int q = 0; q < 4; ++q)
                            acc[q] = __builtin_amdgcn_mfma_f32_32x32x16_f16(
                                ar[q - ah + 2], b, acc[q], 0, 0, 0);
                    }
                }
            }
        }
        if (ph == 0) __syncthreads();   // protect LDS before re-staging
    }

    // epilogue. C/D (HW-verified): col(cout)=lane&31, row(w)=(reg&3)+8*(reg>>2)+4*hi
    #pragma unroll
    for (int q = 0; q < 4; ++q) {
        const int hrow = hb + q;
        if (hrow >= DOUT) continue;
        const size_t rowbase = (((size_t)(n * DOUT + d)) * DOUT + hrow) * (DOUT * COUT);
        const int cout = wv * 32 + col;
        float ls = 0.f, lsq = 0.f;
        #pragma unroll
        for (int reg = 0; reg < 16; ++reg) {
            const int wout = (reg & 3) + 8 * (reg >> 2) + 4 * hi;
            float v = fmaxf(acc[q][reg], 0.0f);
            if (wout < DOUT) {
                y[rowbase + (size_t)wout * COUT + cout] = v;
                ls += v; lsq += v * v;
            }
        }
        // cohort sharing one GN group: same (col>>4) -> xor {1,2,4,8,32}
        #pragma unroll
        for (int off = 1; off < 16; off <<= 1) {
            ls  += __shfl_xor(ls, off);
            lsq += __shfl_xor(lsq, off);
        }
        ls  += __shfl_xor(ls, 32);
        lsq += __shfl_xor(lsq, 32);
        if (lane == 0 || lane == 16) {
            const int g = wv * 2 + (col >> 4);   // 8 groups of 16 couts
            atomicAdd(&gsum[g], ls);
            atomicAdd(&gsq[g], lsq);
        }
    }
    __syncthreads();
    if (tid < NGRP) {
        atomicAdd(&stats[(n * NGRP + tid) * 2 + 0], gsum[tid]);
        atomicAdd(&stats[(n * NGRP + tid) * 2 + 1], gsq[tid]);
    }
}

// ---- elementwise normalize (round-5 proven form) ----
__global__ __launch_bounds__(256) void gn_apply_kernel(
    float* __restrict__ y, const float* __restrict__ stats,
    const float* __restrict__ scale, const float* __restrict__ bias)
{
    const int total4 = N_ * DOUT * DOUT * DOUT * (COUT / 4);
    int i = blockIdx.x * 256 + threadIdx.x;
    if (i >= total4) return;

    const int t  = i & 31;
    const int co = t * 4;
    const int g  = t >> 2;
    const int n  = i / (DOUT * DOUT * DOUT * (COUT / 4));

    const float s  = stats[(n * NGRP + g) * 2 + 0];
    const float sq = stats[(n * NGRP + g) * 2 + 1];
    const float invN = 1.0f / (float)(DOUT * DOUT * DOUT * (COUT / NGRP));
    const float mean = s * invN;
    const float var  = sq * invN - mean * mean;
    const float rstd = rsqrtf(var + EPS);

    float4 v = ((float4*)y)[i];
    const float4 sc = *(const float4*)(scale + co);
    const float4 bi = *(const float4*)(bias + co);
    v.x = (v.x - mean) * rstd * sc.x + bi.x;
    v.y = (v.y - mean) * rstd * sc.y + bi.y;
    v.z = (v.z - mean) * rstd * sc.z + bi.z;
    v.w = (v.w - mean) * rstd * sc.w + bi.w;
    ((float4*)y)[i] = v;
}

extern "C" void kernel_launch(void* const* d_in, const int* in_sizes, int n_in,
                              void* d_out, int out_size, void* d_ws, size_t ws_size,
                              hipStream_t stream) {
    const float* x     = (const float*)d_in[0];
    const float* K     = (const float*)d_in[1];
    const float* scale = (const float*)d_in[2];
    const float* bias  = (const float*)d_in[3];
    float* y = (float*)d_out;

    float*    stats = (float*)((char*)d_ws + STATS_OFF);
    _Float16* Kf    = (_Float16*)((char*)d_ws + KF_OFF);

    convert_k_kernel<<<108, 256, 0, stream>>>(K, Kf, stats);
    conv_mfma_kernel<<<N_ * DOUT * 7, 256, 0, stream>>>(x, Kf, y, stats);
    const int total4 = N_ * DOUT * DOUT * DOUT * (COUT / 4);
    gn_apply_kernel<<<(total4 + 255) / 256, 256, 0, stream>>>(y, stats, scale, bias);
}

// Round 9
// 345.357 us; speedup vs baseline: 1.0378x; 1.0323x over previous
//
#include <hip/hip_runtime.h>

#define N_    16
#define DIN   24
#define DOUT  26
#define CIN   64
#define COUT  128
#define NGRP  8
#define EPS   1e-5f

// ws layout (bytes):
//   [0, 1024)            : float stats[N_][NGRP][2] (sum, sumsq) -- zeroed each launch
//   [1280, 443648)       : fp16 Kf[27][4][4][64][8]  (32x32 MFMA B-fragment order)
//   [1048576, 73039872)  : fp16 y16[N][26][26][26][128] -- OPTIONAL intermediate,
//                          only if ws_size >= Y16_END; else round-5 fp32 path runs.
#define STATS_OFF 0
#define KF_OFF    1280
#define Y16_OFF   1048576
#define Y16_BYTES ((size_t)N_ * DOUT * DOUT * DOUT * COUT * 2)   // 71,991,296
#define Y16_END   ((size_t)Y16_OFF + Y16_BYTES)                  // 73,039,872

typedef _Float16 half8_t  __attribute__((ext_vector_type(8)));
typedef float    f32x16_t __attribute__((ext_vector_type(16)));

// ---- build Kf in 32x32x16 B-fragment order + zero stats ----
// frag (tap, ckg, nf): element j of lane: k(ci) = ckg*16 + (lane>>5)*8 + j,
// n(co) = nf*32 + (lane&31).   t = ((tap*4 + ckg)*4 + nf)*64 + lane.
__global__ __launch_bounds__(256) void convert_k_kernel(
    const float* __restrict__ K, _Float16* __restrict__ Kf, float* __restrict__ stats)
{
    int t = blockIdx.x * 256 + threadIdx.x;
    if (blockIdx.x == 0 && threadIdx.x < N_ * NGRP * 2) stats[threadIdx.x] = 0.0f;
    if (t >= 27 * 4 * 4 * 64) return;
    const int lane = t & 63;
    const int nf   = (t >> 6) & 3;
    const int ckg  = (t >> 8) & 3;
    const int tap  = t >> 10;                        // 0..26 = ad*9+ah*3+aw
    const int ci0  = ckg * 16 + (lane >> 5) * 8;
    const int co   = nf * 32 + (lane & 31);
    half8_t h;
    #pragma unroll
    for (int j = 0; j < 8; ++j)
        h[j] = (_Float16)K[(size_t)(tap * CIN + ci0 + j) * COUT + co];
    *(half8_t*)(Kf + (size_t)t * 8) = h;
}

// ==== conv + ReLU + group sums. Wave = one cout-frag (nf=wv), M = 4 h-rows ====
// ROUND-5 PROVEN STRUCTURE (179 us, VGPR 84, no spill). Round-8's A-row
// register cache REGRESSED (192 us, VGPR dropped to 56: compiler serialized
// the 6-load burst against dependent MFMAs instead of pipelining; and bank
// conflicts were unchanged -> they live in staging ds_writes, reads were
// never critical). Keep the interleaved per-MFMA ds_read form.
// Block (n, d, h-quad), NATURAL order (round-3: XCD swizzle destroyed L2).
// acc[4] = 64 AGPRs (unified file); (256,4) cap 128 -> spill; (256,3) OK.
// FP16-INTERMEDIATE (round-9): epilogue stores y16 (72 MB) instead of fp32 y
// (144 MB); stats still from unrounded fp32 acc. Halves conv write traffic
// and gn read traffic. 32 consecutive lanes x 2 B = 64 B contiguous/store.
__global__ __launch_bounds__(256, 3) void conv_mfma16_kernel(
    const float* __restrict__ x, const _Float16* __restrict__ Kf,
    _Float16* __restrict__ y16, float* __restrict__ stats)
{
    __shared__ __align__(16) _Float16 xs[18 * 28 * 40];   // 40,320 B
    __shared__ float gsum[NGRP], gsq[NGRP];

    const int bid = blockIdx.x;
    const int n   = bid / (DOUT * 7);
    const int rem = bid % (DOUT * 7);
    const int d   = rem / 7;
    const int hb  = (rem % 7) * 4;
    const int tid = threadIdx.x;

    if (tid < NGRP) { gsum[tid] = 0.0f; gsq[tid] = 0.0f; }

    const int lane = tid & 63;
    const int wv   = tid >> 6;          // nf: couts wv*32 .. wv*32+31
    const int col  = lane & 31;         // A: m(=w) ; B/C/D: n(cout in frag)
    const int hi   = lane >> 5;         // k-half selector

    int aofs[3];
    #pragma unroll
    for (int aw = 0; aw < 3; ++aw) {
        int sl = col - aw + 2; if (sl > 27) sl = 27;   // slot 27 always zero-staged
        aofs[aw] = sl * 40 + hi * 8;
    }

    f32x16_t acc[4];
    #pragma unroll
    for (int q = 0; q < 4; ++q) acc[q] = (f32x16_t)(0.0f);

    const _Float16* Kfl = Kf + (size_t)lane * 8 + (size_t)wv * 512;

    for (int ph = 0; ph < 2; ++ph) {
        // ---- stage this phase's 32 ci: 18*28*4 = 2016 16-B chunks ----
        for (int c = tid; c < 2016; c += 256) {
            const int s    = c / 112;        // s = ad*6 + hs
            const int rr   = c % 112;
            const int slot = rr >> 2;        // source w = slot - 2
            const int ch   = rr & 3;
            const int dd = d - s / 6;
            const int hh = hb + (s % 6) - 2;
            const int w  = slot - 2;
            half8_t v = {};
            if (dd >= 0 && dd < DIN && hh >= 0 && hh < DIN && w >= 0 && w < DIN) {
                const float* src = x + ((size_t)(((n * DIN + dd) * DIN + hh) * DIN + w)) * CIN
                                     + ph * 32 + ch * 8;
                const float4 a = *(const float4*)(src);
                const float4 b = *(const float4*)(src + 4);
                v[0] = (_Float16)a.x; v[1] = (_Float16)a.y; v[2] = (_Float16)a.z; v[3] = (_Float16)a.w;
                v[4] = (_Float16)b.x; v[5] = (_Float16)b.y; v[6] = (_Float16)b.z; v[7] = (_Float16)b.w;
            }
            *(half8_t*)(xs + s * 1120 + slot * 40 + ch * 8) = v;
        }
        __syncthreads();

        // ---- all 27 taps, 2 k16-steps within this ci-half ----
        for (int ad = 0; ad < 3; ++ad) {
            #pragma unroll
            for (int ah = 0; ah < 3; ++ah) {
                const int sb  = (ad * 6 - ah + 2) * 1120;   // + q*1120 per h-row
                const int tap = (ad * 3 + ah) * 3;
                #pragma unroll
                for (int aw = 0; aw < 3; ++aw) {
                    #pragma unroll
                    for (int ck = 0; ck < 2; ++ck) {
                        half8_t b = *(const half8_t*)(
                            Kfl + (size_t)(((tap + aw) * 4 + ph * 2 + ck) * 4) * 512);
                        #pragma unroll
                        for (int q = 0; q < 4; ++q) {
                            half8_t a = *(const half8_t*)(xs + sb + q * 1120 + aofs[aw] + ck * 16);
                            acc[q] = __builtin_amdgcn_mfma_f32_32x32x16_f16(a, b, acc[q], 0, 0, 0);
                        }
                    }
                }
            }
        }
        if (ph == 0) __syncthreads();   // protect LDS before re-staging
    }

    // epilogue. C/D (HW-verified): col(cout)=lane&31, row(w)=(reg&3)+8*(reg>>2)+4*hi
    #pragma unroll
    for (int q = 0; q < 4; ++q) {
        const int hrow = hb + q;
        if (hrow >= DOUT) continue;
        const size_t rowbase = (((size_t)(n * DOUT + d)) * DOUT + hrow) * (DOUT * COUT);
        const int cout = wv * 32 + col;
        float ls = 0.f, lsq = 0.f;
        #pragma unroll
        for (int reg = 0; reg < 16; ++reg) {
            const int wout = (reg & 3) + 8 * (reg >> 2) + 4 * hi;
            float v = fmaxf(acc[q][reg], 0.0f);
            if (wout < DOUT) {
                y16[rowbase + (size_t)wout * COUT + cout] = (_Float16)v;
                ls += v; lsq += v * v;
            }
        }
        // cohort sharing one GN group: same (col>>4) -> xor {1,2,4,8,32}
        #pragma unroll
        for (int off = 1; off < 16; off <<= 1) {
            ls  += __shfl_xor(ls, off);
            lsq += __shfl_xor(lsq, off);
        }
        ls  += __shfl_xor(ls, 32);
        lsq += __shfl_xor(lsq, 32);
        if (lane == 0 || lane == 16) {
            const int g = wv * 2 + (col >> 4);   // 8 groups of 16 couts
            atomicAdd(&gsum[g], ls);
            atomicAdd(&gsq[g], lsq);
        }
    }
    __syncthreads();
    if (tid < NGRP) {
        atomicAdd(&stats[(n * NGRP + tid) * 2 + 0], gsum[tid]);
        atomicAdd(&stats[(n * NGRP + tid) * 2 + 1], gsq[tid]);
    }
}

// ---- normalize from fp16 intermediate: read y16 (72 MB), write fp32 y (144 MB) ----
// chunk = 8 couts; 16 chunks per spatial position; chunk i covers couts
// (i&15)*8..+7, all within one GN group (g = (i&15)>>1).
__global__ __launch_bounds__(256) void gn16_apply_kernel(
    const _Float16* __restrict__ y16, float* __restrict__ y,
    const float* __restrict__ stats,
    const float* __restrict__ scale, const float* __restrict__ bias)
{
    const int total8 = N_ * DOUT * DOUT * DOUT * (COUT / 8);   // 4,499,456
    int i = blockIdx.x * 256 + threadIdx.x;
    if (i >= total8) return;

    const int t  = i & 15;
    const int co = t * 8;
    const int g  = t >> 1;
    const int n  = i / (DOUT * DOUT * DOUT * (COUT / 8));      // / 281,216

    const float s  = stats[(n * NGRP + g) * 2 + 0];
    const float sq = stats[(n * NGRP + g) * 2 + 1];
    const float invN = 1.0f / (float)(DOUT * DOUT * DOUT * (COUT / NGRP));
    const float mean = s * invN;
    const float rstd = rsqrtf(sq * invN - mean * mean + EPS);

    const half8_t h = *(const half8_t*)(y16 + (size_t)i * 8);
    const float4 sc0 = *(const float4*)(scale + co);
    const float4 sc1 = *(const float4*)(scale + co + 4);
    const float4 bi0 = *(const float4*)(bias + co);
    const float4 bi1 = *(const float4*)(bias + co + 4);

    float4 o0, o1;
    o0.x = ((float)h[0] - mean) * rstd * sc0.x + bi0.x;
    o0.y = ((float)h[1] - mean) * rstd * sc0.y + bi0.y;
    o0.z = ((float)h[2] - mean) * rstd * sc0.z + bi0.z;
    o0.w = ((float)h[3] - mean) * rstd * sc0.w + bi0.w;
    o1.x = ((float)h[4] - mean) * rstd * sc1.x + bi1.x;
    o1.y = ((float)h[5] - mean) * rstd * sc1.y + bi1.y;
    o1.z = ((float)h[6] - mean) * rstd * sc1.z + bi1.z;
    o1.w = ((float)h[7] - mean) * rstd * sc1.w + bi1.w;
    ((float4*)y)[(size_t)i * 2]     = o0;
    ((float4*)y)[(size_t)i * 2 + 1] = o1;
}

// ==== FALLBACK PATH (round-5 proven, verbatim): fp32 y throughout ====
__global__ __launch_bounds__(256, 3) void conv_mfma_kernel(
    const float* __restrict__ x, const _Float16* __restrict__ Kf,
    float* __restrict__ y, float* __restrict__ stats)
{
    __shared__ __align__(16) _Float16 xs[18 * 28 * 40];   // 40,320 B
    __shared__ float gsum[NGRP], gsq[NGRP];

    const int bid = blockIdx.x;
    const int n   = bid / (DOUT * 7);
    const int rem = bid % (DOUT * 7);
    const int d   = rem / 7;
    const int hb  = (rem % 7) * 4;
    const int tid = threadIdx.x;

    if (tid < NGRP) { gsum[tid] = 0.0f; gsq[tid] = 0.0f; }

    const int lane = tid & 63;
    const int wv   = tid >> 6;
    const int col  = lane & 31;
    const int hi   = lane >> 5;

    int aofs[3];
    #pragma unroll
    for (int aw = 0; aw < 3; ++aw) {
        int sl = col - aw + 2; if (sl > 27) sl = 27;
        aofs[aw] = sl * 40 + hi * 8;
    }

    f32x16_t acc[4];
    #pragma unroll
    for (int q = 0; q < 4; ++q) acc[q] = (f32x16_t)(0.0f);

    const _Float16* Kfl = Kf + (size_t)lane * 8 + (size_t)wv * 512;

    for (int ph = 0; ph < 2; ++ph) {
        for (int c = tid; c < 2016; c += 256) {
            const int s    = c / 112;
            const int rr   = c % 112;
            const int slot = rr >> 2;
            const int ch   = rr & 3;
            const int dd = d - s / 6;
            const int hh = hb + (s % 6) - 2;
            const int w  = slot - 2;
            half8_t v = {};
            if (dd >= 0 && dd < DIN && hh >= 0 && hh < DIN && w >= 0 && w < DIN) {
                const float* src = x + ((size_t)(((n * DIN + dd) * DIN + hh) * DIN + w)) * CIN
                                     + ph * 32 + ch * 8;
                const float4 a = *(const float4*)(src);
                const float4 b = *(const float4*)(src + 4);
                v[0] = (_Float16)a.x; v[1] = (_Float16)a.y; v[2] = (_Float16)a.z; v[3] = (_Float16)a.w;
                v[4] = (_Float16)b.x; v[5] = (_Float16)b.y; v[6] = (_Float16)b.z; v[7] = (_Float16)b.w;
            }
            *(half8_t*)(xs + s * 1120 + slot * 40 + ch * 8) = v;
        }
        __syncthreads();

        for (int ad = 0; ad < 3; ++ad) {
            #pragma unroll
            for (int ah = 0; ah < 3; ++ah) {
                const int sb  = (ad * 6 - ah + 2) * 1120;
                const int tap = (ad * 3 + ah) * 3;
                #pragma unroll
                for (int aw = 0; aw < 3; ++aw) {
                    #pragma unroll
                    for (int ck = 0; ck < 2; ++ck) {
                        half8_t b = *(const half8_t*)(
                            Kfl + (size_t)(((tap + aw) * 4 + ph * 2 + ck) * 4) * 512);
                        #pragma unroll
                        for (int q = 0; q < 4; ++q) {
                            half8_t a = *(const half8_t*)(xs + sb + q * 1120 + aofs[aw] + ck * 16);
                            acc[q] = __builtin_amdgcn_mfma_f32_32x32x16_f16(a, b, acc[q], 0, 0, 0);
                        }
                    }
                }
            }
        }
        if (ph == 0) __syncthreads();
    }

    #pragma unroll
    for (int q = 0; q < 4; ++q) {
        const int hrow = hb + q;
        if (hrow >= DOUT) continue;
        const size_t rowbase = (((size_t)(n * DOUT + d)) * DOUT + hrow) * (DOUT * COUT);
        const int cout = wv * 32 + col;
        float ls = 0.f, lsq = 0.f;
        #pragma unroll
        for (int reg = 0; reg < 16; ++reg) {
            const int wout = (reg & 3) + 8 * (reg >> 2) + 4 * hi;
            float v = fmaxf(acc[q][reg], 0.0f);
            if (wout < DOUT) {
                y[rowbase + (size_t)wout * COUT + cout] = v;
                ls += v; lsq += v * v;
            }
        }
        #pragma unroll
        for (int off = 1; off < 16; off <<= 1) {
            ls  += __shfl_xor(ls, off);
            lsq += __shfl_xor(lsq, off);
        }
        ls  += __shfl_xor(ls, 32);
        lsq += __shfl_xor(lsq, 32);
        if (lane == 0 || lane == 16) {
            const int g = wv * 2 + (col >> 4);
            atomicAdd(&gsum[g], ls);
            atomicAdd(&gsq[g], lsq);
        }
    }
    __syncthreads();
    if (tid < NGRP) {
        atomicAdd(&stats[(n * NGRP + tid) * 2 + 0], gsum[tid]);
        atomicAdd(&stats[(n * NGRP + tid) * 2 + 1], gsq[tid]);
    }
}

__global__ __launch_bounds__(256) void gn_apply_kernel(
    float* __restrict__ y, const float* __restrict__ stats,
    const float* __restrict__ scale, const float* __restrict__ bias)
{
    const int total4 = N_ * DOUT * DOUT * DOUT * (COUT / 4);
    int i = blockIdx.x * 256 + threadIdx.x;
    if (i >= total4) return;

    const int t  = i & 31;
    const int co = t * 4;
    const int g  = t >> 2;
    const int n  = i / (DOUT * DOUT * DOUT * (COUT / 4));

    const float s  = stats[(n * NGRP + g) * 2 + 0];
    const float sq = stats[(n * NGRP + g) * 2 + 1];
    const float invN = 1.0f / (float)(DOUT * DOUT * DOUT * (COUT / NGRP));
    const float mean = s * invN;
    const float var  = sq * invN - mean * mean;
    const float rstd = rsqrtf(var + EPS);

    float4 v = ((float4*)y)[i];
    const float4 sc = *(const float4*)(scale + co);
    const float4 bi = *(const float4*)(bias + co);
    v.x = (v.x - mean) * rstd * sc.x + bi.x;
    v.y = (v.y - mean) * rstd * sc.y + bi.y;
    v.z = (v.z - mean) * rstd * sc.z + bi.z;
    v.w = (v.w - mean) * rstd * sc.w + bi.w;
    ((float4*)y)[i] = v;
}

extern "C" void kernel_launch(void* const* d_in, const int* in_sizes, int n_in,
                              void* d_out, int out_size, void* d_ws, size_t ws_size,
                              hipStream_t stream) {
    const float* x     = (const float*)d_in[0];
    const float* K     = (const float*)d_in[1];
    const float* scale = (const float*)d_in[2];
    const float* bias  = (const float*)d_in[3];
    float* y = (float*)d_out;

    float*    stats = (float*)((char*)d_ws + STATS_OFF);
    _Float16* Kf    = (_Float16*)((char*)d_ws + KF_OFF);
    _Float16* y16   = (_Float16*)((char*)d_ws + Y16_OFF);

    convert_k_kernel<<<108, 256, 0, stream>>>(K, Kf, stats);

    if (ws_size >= Y16_END) {
        conv_mfma16_kernel<<<N_ * DOUT * 7, 256, 0, stream>>>(x, Kf, y16, stats);
        const int total8 = N_ * DOUT * DOUT * DOUT * (COUT / 8);
        gn16_apply_kernel<<<(total8 + 255) / 256, 256, 0, stream>>>(y16, y, stats, scale, bias);
    } else {
        conv_mfma_kernel<<<N_ * DOUT * 7, 256, 0, stream>>>(x, Kf, y, stats);
        const int total4 = N_ * DOUT * DOUT * DOUT * (COUT / 4);
        gn_apply_kernel<<<(total4 + 255) / 256, 256, 0, stream>>>(y, stats, scale, bias);
    }
}